// Round 14
// baseline (333.546 us; speedup 1.0000x reference)
//
#include <hip/hip_runtime.h>

// Problem constants
#define NB    2048   // n_back (k)
#define NB4   512    // NB/4 in f32x4 units
#define NOUT  2048   // H*W*COUT
#define NDIM  2048   // H*W*CIN

// Output flat offsets (floats) in d_out: [w_u_, b_u_, w_l_, b_l_]
#define OFF_BU  16777216ull
#define OFF_WL  16785408ull
#define OFF_BL  33562624ull

// ws layout (floats): [0,16384) bias partials (2,4,2048); [16384,+1728) T3
#define WS_T    16384

typedef float f32x4 __attribute__((ext_vector_type(4)));

// T3[v][co][ci*9+kh*3+kw], v=0 full, v=1 left-edge (kw==2 zeroed, for wi=0),
// v=2 right-edge (kw==0 zeroed, for wi=15). Per (v,co): 72 contiguous floats
// -> wide s_load batches (round-10 mechanism). Variants make ALL input loads
// unconditional (clamped addresses load garbage that meets a zero weight).
__global__ void prep_kernel(const float* __restrict__ kern, float* __restrict__ T) {
    const int i = blockIdx.x * 64 + threadIdx.x;   // 0..1727
    if (i < 1728) {
        const int v  = i / 576, r = i % 576;
        const int kw = r % 3, kh = (r / 3) % 3, ci = (r / 9) % 8, co = r / 72;
        float val = kern[((kh * 3 + kw) * 8 + ci) * 8 + co];
        if ((v == 1 && kw == 2) || (v == 2 && kw == 0)) val = 0.f;
        T[i] = val;
    }
}

// co-outer conv-backward, f32x4 lanes, 2 owned rows/thread, batched loads,
// SOFTWARE-PIPELINED co loop: uB loads for co+1 issue before the FMA phase
// of co -> ~300cy of FMA covers the LLC round trip (round-13 showed ~47us
// of VMEM stall at ~2 resident waves/SIMD; per-wave ILP is the only lever).
// VGPR target ~170 under launch_bounds(256,2) — residency was already 2.
__global__ __launch_bounds__(256, 2) void conv_back_kernel(
    const float* __restrict__ wu,
    const float* __restrict__ wl,
    const float* __restrict__ Tw,     // (3v, 8co, 72) weight variants
    const float* __restrict__ bias,   // (8)
    float* __restrict__ outbuf,       // full d_out base
    float* __restrict__ bias_ws)      // (2,4,2048) partial bias sums
{
    const int bid = blockIdx.x;            // 0..2047
    const int klo = bid & 7;               // XCD id = k-chunk (k-disjoint)
    const int j   = bid >> 3;              // per-XCD order
    const int wig = j & 3;                 // wi group
    const int hr  = (j >> 2) & 7;          // 2-row group
    const int sl  = j >> 5;                // 0..7 (t,b)
    const int t = sl >> 2, b = sl & 3;
    const int kl  = threadIdx.x & 63;
    const int sub = threadIdx.x >> 6;      // 0..3
    const int wi  = wig * 4 + sub;         // 0..15, wave-uniform
    const int r0  = hr * 2;                // first owned out row
    const int k4  = klo * 64 + kl;         // f32x4 index over k, 0..511

    const f32x4* __restrict__ in =
        (const f32x4*)(t ? wl : wu) + (size_t)b * NOUT * NB4 + k4;
    f32x4* __restrict__ wout =
        (f32x4*)(outbuf + (t ? OFF_WL : 0)) + (size_t)b * NDIM * NB4 + k4;

    // wave-uniform edge handling, computed ONCE:
    // clamped column offsets (f32x4 units) + weight-variant base pointer
    const long dlo = (wi > 0)  ? -(long)(8 * NB4) : 0;
    const long dhi = (wi < 15) ?  (long)(8 * NB4) : 0;
    const float* __restrict__ Tsel =
        Tw + 576 * (wi == 0 ? 1 : (wi == 15 ? 2 : 0));

    // row validity/offsets (block-uniform), once
    bool   rv[4];
    size_t rowoff[4];
    #pragma unroll
    for (int s = 0; s < 4; ++s) {
        const int ho = r0 - 1 + s;
        rv[s] = ((unsigned)ho < 16u);
        rowoff[s] = rv[s] ? (size_t)(ho * 128) * NB4 : 0;
    }
    const size_t cb = (size_t)(wi * 8) * NB4;

    f32x4 acc[2][8];
    #pragma unroll
    for (int m = 0; m < 2; ++m)
        #pragma unroll
        for (int ci = 0; ci < 8; ++ci) acc[m][ci] = (f32x4)(0.f);
    f32x4 pb = (f32x4)(0.f);

    f32x4 uA[4][3], uB[4][3];

    auto load = [&](int co, f32x4 (&u)[4][3]) {
        #pragma unroll
        for (int s = 0; s < 4; ++s) {
            if (rv[s]) {   // block-uniform branch; loads unconditional
                const f32x4* p = in + rowoff[s] + cb + (size_t)co * NB4;
                u[s][0] = *(p + dlo);
                u[s][1] = *p;
                u[s][2] = *(p + dhi);
            } else {
                u[s][0] = (f32x4)(0.f);
                u[s][1] = (f32x4)(0.f);
                u[s][2] = (f32x4)(0.f);
            }
        }
    };

    auto fmaph = [&](int co, const f32x4 (&u)[4][3]) {
        const float* __restrict__ tb = Tsel + co * 72;   // uniform -> s_loads
        const float bco = bias[co];
        pb += bco * (u[1][1] + u[2][1]);   // owned rows s=1,2 center col
        #pragma unroll
        for (int s = 0; s < 4; ++s)
            #pragma unroll
            for (int kh = 0; kh < 3; ++kh) {
                const int m = s - 2 + kh;           // target owned row
                if (m >= 0 && m <= 1) {             // compile-time filter
                    #pragma unroll
                    for (int ci = 0; ci < 8; ++ci)
                        #pragma unroll
                        for (int kw = 0; kw < 3; ++kw) {
                            const float Kv = tb[ci * 9 + kh * 3 + kw];
                            const f32x4 wv = (f32x4)(Kv);   // splat -> pk fma
                            acc[m][ci] += wv * u[s][2 - kw]; // dw = 1-kw
                        }
                }
            }
    };

    load(0, uA);
    #pragma unroll 1
    for (int c2 = 0; c2 < 4; ++c2) {
        const int co = c2 * 2;
        load(co + 1, uB);        // prefetch odd batch
        fmaph(co, uA);           // compute even (covers uB flight)
        if (co + 2 < 8)
            load(co + 2, uA);    // prefetch next even batch
        fmaph(co + 1, uB);       // compute odd (covers uA flight)
    }

    #pragma unroll
    for (int m = 0; m < 2; ++m)
        #pragma unroll
        for (int ci = 0; ci < 8; ++ci)
            wout[(size_t)(((r0 + m) * 16 + wi) * 8 + ci) * NB4] = acc[m][ci];

    // reduce bias partials across the 4 sub-waves (same k4, different wi)
    __shared__ f32x4 red[4][64];
    red[sub][kl] = pb;
    __syncthreads();
    if (sub == 0) {
        f32x4 tot = red[0][kl] + red[1][kl] + red[2][kl] + red[3][kl];
        float* bws = bias_ws + t * 8192 + b * 2048 + 4 * k4;
        atomicAdd(bws + 0, tot.x);
        atomicAdd(bws + 1, tot.y);
        atomicAdd(bws + 2, tot.z);
        atomicAdd(bws + 3, tot.w);
    }
}

// b_out_ = b_in + ws ; 16384 outputs (2 ul * 4 b * 2048 k)
__global__ void bias_finalize(const float* __restrict__ bu,
                              const float* __restrict__ bl,
                              const float* __restrict__ ws,
                              float* __restrict__ out)
{
    const int idx = blockIdx.x * blockDim.x + threadIdx.x;   // 0..16383
    const int ul  = idx >> 13;
    const int r   = idx & 8191;                              // b*2048 + k
    const float* bin = ul ? bl : bu;
    const size_t off = ul ? OFF_BL : OFF_BU;
    out[off + r] = bin[r] + ws[(size_t)ul * 8192 + r];
}

extern "C" void kernel_launch(void* const* d_in, const int* in_sizes, int n_in,
                              void* d_out, int out_size, void* d_ws, size_t ws_size,
                              hipStream_t stream) {
    // inputs: 0=x (unused), 1=kernel, 2=bias, 3=w_out_u, 4=b_out_u, 5=w_out_l, 6=b_out_l
    const float* kern = (const float*)d_in[1];
    const float* bias = (const float*)d_in[2];
    const float* wu   = (const float*)d_in[3];
    const float* bu   = (const float*)d_in[4];
    const float* wl   = (const float*)d_in[5];
    const float* bl   = (const float*)d_in[6];
    float* out = (float*)d_out;
    float* ws  = (float*)d_ws;

    // zero the 64 KB bias-partial region (graph replays re-run this node)
    (void)hipMemsetAsync(ws, 0, 2ull * 4 * NB * sizeof(float), stream);

    prep_kernel<<<27, 64, 0, stream>>>(kern, ws + WS_T);
    conv_back_kernel<<<dim3(2048), dim3(256), 0, stream>>>(wu, wl, ws + WS_T, bias, out, ws);
    bias_finalize<<<64, 256, 0, stream>>>(bu, bl, ws, out);
}

// Round 15
// 126.084 us; speedup vs baseline: 2.6454x; 2.6454x over previous
//
#include <hip/hip_runtime.h>

// Problem constants
#define NB    2048   // n_back (k)
#define NB4   512    // NB/4 in f32x4 units
#define NOUT  2048   // H*W*COUT
#define NDIM  2048   // H*W*CIN

// Output flat offsets (floats) in d_out: [w_u_, b_u_, w_l_, b_l_]
#define OFF_BU  16777216ull
#define OFF_WL  16785408ull
#define OFF_BL  33562624ull

// ws layout (floats): [0,16384) bias partials (2,4,2048); [16384,+1728) T3
#define WS_T    16384

typedef float f32x4 __attribute__((ext_vector_type(4)));

// T3[v][co][ci*9+kh*3+kw], v=0 full, v=1 left-edge (kw==2 zeroed, wi==0),
// v=2 right-edge (kw==0 zeroed, wi==15). Per (v,co): 72 contiguous floats
// -> wide s_load batches. Variants make ALL input loads unconditional
// (clamped addresses load garbage that multiplies a zero weight).
__global__ void prep_kernel(const float* __restrict__ kern, float* __restrict__ T) {
    const int i = blockIdx.x * 64 + threadIdx.x;   // 0..1727
    if (i < 1728) {
        const int v  = i / 576, r = i % 576;
        const int kw = r % 3, kh = (r / 3) % 3, ci = (r / 9) % 8, co = r / 72;
        float val = kern[((kh * 3 + kw) * 8 + ci) * 8 + co];
        if ((v == 1 && kw == 2) || (v == 2 && kw == 0)) val = 0.f;
        T[i] = val;
    }
}

// co-outer conv-backward, f32x4 lanes, 2 owned rows/thread, batched loads.
// ROUND-14 LESSON: wi was wave- but not BLOCK-uniform -> Tsel divergent ->
// weights demoted SGPR->VMEM (SGPR 112->48), spill, 360us. THIS ROUND:
// wi moves to blockIdx (all 4 waves same wi, threads span k). Tsel / edge
// offsets / row masks are all block-uniform scalars; weights stay in
// SGPRs; load+store addresses = scalar base + k4*16 (one v_lshlrev total,
// no per-lane address chains); zero per-lane edge selects.
__global__ __launch_bounds__(256, 2) void conv_back_kernel(
    const float* __restrict__ wu,
    const float* __restrict__ wl,
    const float* __restrict__ Tw,     // (3v, 8co, 72) weight variants
    const float* __restrict__ bias,   // (8)
    float* __restrict__ outbuf,       // full d_out base
    float* __restrict__ bias_ws)      // (2,4,2048) partial bias sums
{
    const int bid = blockIdx.x;            // 0..2047
    const int kc  = bid & 1;               // k half
    const int hr  = (bid >> 1) & 7;        // 2-row group
    const int wi  = (bid >> 4) & 15;       // BLOCK-uniform wi
    const int sl  = bid >> 8;              // 0..7 (t,b)
    const int t = sl >> 2, b = sl & 3;
    const int r0  = hr * 2;                // first owned out row
    const int k4  = kc * 256 + threadIdx.x;  // f32x4 index over k, 0..511

    const f32x4* __restrict__ in =
        (const f32x4*)(t ? wl : wu) + (size_t)b * NOUT * NB4 + k4;
    f32x4* __restrict__ wout =
        (f32x4*)(outbuf + (t ? OFF_WL : 0)) + (size_t)b * NDIM * NB4 + k4;

    // block-uniform edge handling (scalar): clamped col offsets + variant
    const long dlo = (wi > 0)  ? -(long)(8 * NB4) : 0;
    const long dhi = (wi < 15) ?  (long)(8 * NB4) : 0;
    const float* __restrict__ Tsel =
        Tw + 576 * (wi == 0 ? 1 : (wi == 15 ? 2 : 0));

    // block-uniform row validity/offsets
    bool   rv[4];
    size_t rowoff[4];
    #pragma unroll
    for (int s = 0; s < 4; ++s) {
        const int ho = r0 - 1 + s;
        rv[s] = ((unsigned)ho < 16u);
        rowoff[s] = rv[s] ? (size_t)(ho * 128) * NB4 : 0;
    }
    const size_t cb = (size_t)(wi * 8) * NB4;   // block-uniform column base

    f32x4 acc[2][8];
    #pragma unroll
    for (int m = 0; m < 2; ++m)
        #pragma unroll
        for (int ci = 0; ci < 8; ++ci) acc[m][ci] = (f32x4)(0.f);
    f32x4 pb = (f32x4)(0.f);

    #pragma unroll 1
    for (int co = 0; co < 8; ++co) {
        const float* __restrict__ tb = Tsel + co * 72;  // uniform -> s_loads
        const float bco = bias[co];

        // ---- batched load phase: 12 unconditional loads (scalar-masked rows)
        f32x4 u[4][3];                      // [s][wi-1, wi, wi+1]
        #pragma unroll
        for (int s = 0; s < 4; ++s) {
            if (rv[s]) {                    // block-uniform branch
                const f32x4* p = in + rowoff[s] + cb + (size_t)co * NB4;
                u[s][0] = p[dlo];
                u[s][1] = p[0];
                u[s][2] = p[dhi];
            } else {
                u[s][0] = (f32x4)(0.f);
                u[s][1] = (f32x4)(0.f);
                u[s][2] = (f32x4)(0.f);
            }
        }

        // owned rows are s=1 (r0) and s=2 (r0+1), center column
        pb += bco * (u[1][1] + u[2][1]);

        // ---- FMA phase: 288 f32x4 FMAs consuming the batch ----
        #pragma unroll
        for (int s = 0; s < 4; ++s)
            #pragma unroll
            for (int kh = 0; kh < 3; ++kh) {
                const int m = s - 2 + kh;           // target owned row
                if (m >= 0 && m <= 1) {             // compile-time filter
                    #pragma unroll
                    for (int ci = 0; ci < 8; ++ci)
                        #pragma unroll
                        for (int kw = 0; kw < 3; ++kw) {
                            const float Kv = tb[ci * 9 + kh * 3 + kw]; // SGPR
                            acc[m][ci] += Kv * u[s][2 - kw];   // dw = 1-kw
                        }
                }
            }
    }

    #pragma unroll
    for (int m = 0; m < 2; ++m)
        #pragma unroll
        for (int ci = 0; ci < 8; ++ci)
            wout[(size_t)(((r0 + m) * 16 + wi) * 8 + ci) * NB4] = acc[m][ci];

    // per-thread bias partials (threads own distinct k now; 128 adds/addr)
    float* bws = bias_ws + t * 8192 + b * 2048 + 4 * k4;
    atomicAdd(bws + 0, pb.x);
    atomicAdd(bws + 1, pb.y);
    atomicAdd(bws + 2, pb.z);
    atomicAdd(bws + 3, pb.w);
}

// b_out_ = b_in + ws ; 16384 outputs (2 ul * 4 b * 2048 k)
__global__ void bias_finalize(const float* __restrict__ bu,
                              const float* __restrict__ bl,
                              const float* __restrict__ ws,
                              float* __restrict__ out)
{
    const int idx = blockIdx.x * blockDim.x + threadIdx.x;   // 0..16383
    const int ul  = idx >> 13;
    const int r   = idx & 8191;                              // b*2048 + k
    const float* bin = ul ? bl : bu;
    const size_t off = ul ? OFF_BL : OFF_BU;
    out[off + r] = bin[r] + ws[(size_t)ul * 8192 + r];
}

extern "C" void kernel_launch(void* const* d_in, const int* in_sizes, int n_in,
                              void* d_out, int out_size, void* d_ws, size_t ws_size,
                              hipStream_t stream) {
    // inputs: 0=x (unused), 1=kernel, 2=bias, 3=w_out_u, 4=b_out_u, 5=w_out_l, 6=b_out_l
    const float* kern = (const float*)d_in[1];
    const float* bias = (const float*)d_in[2];
    const float* wu   = (const float*)d_in[3];
    const float* bu   = (const float*)d_in[4];
    const float* wl   = (const float*)d_in[5];
    const float* bl   = (const float*)d_in[6];
    float* out = (float*)d_out;
    float* ws  = (float*)d_ws;

    // zero the 64 KB bias-partial region (graph replays re-run this node)
    (void)hipMemsetAsync(ws, 0, 2ull * 4 * NB * sizeof(float), stream);

    prep_kernel<<<27, 64, 0, stream>>>(kern, ws + WS_T);
    conv_back_kernel<<<dim3(2048), dim3(256), 0, stream>>>(wu, wl, ws + WS_T, bias, out, ws);
    bias_finalize<<<64, 256, 0, stream>>>(bu, bl, ws, out);
}

// Round 16
// 108.184 us; speedup vs baseline: 3.0831x; 1.1655x over previous
//
#include <hip/hip_runtime.h>

// Problem constants
#define NB    2048   // n_back (k)
#define NB4   512    // NB/4 in f32x4 units
#define NOUT  2048   // H*W*COUT
#define NDIM  2048   // H*W*CIN

// Output flat offsets (floats) in d_out: [w_u_, b_u_, w_l_, b_l_]
#define OFF_BU  16777216ull
#define OFF_WL  16785408ull
#define OFF_BL  33562624ull

// ws layout (floats): [0,16384) bias partials (2,4,2048); [16384,+576) T
#define WS_T    16384

typedef float f32x4 __attribute__((ext_vector_type(4)));

// T[co*72 + ci*9 + kh*3 + kw] = kern[((kh*3+kw)*8+ci)*8+co]
// -> per co, 72 CONTIGUOUS floats: block-uniform address -> wide s_load
// into the scalar file (round-10 mechanism; round-14 showed any
// threadIdx-dependence here demotes to VMEM and wrecks everything).
__global__ void prep_kernel(const float* __restrict__ kern, float* __restrict__ T) {
    const int i = blockIdx.x * 64 + threadIdx.x;   // 0..575
    if (i < 576) {
        const int kw = i % 3, kh = (i / 3) % 3, ci = (i / 9) % 8, co = i / 72;
        T[i] = kern[((kh * 3 + kw) * 8 + ci) * 8 + co];
    }
}

// Round-13 structure + (a) saddr+voffset addressing: ONE per-lane 32-bit
// offset vo; every load/store = (uniform base + scalar off) + vo, so
// in-loop address math rides the scalar pipe; (b) double-buffered co loop
// (r14 schedule WITHOUT the divergent-Tsel mistake): next co's 12 loads
// issue before this co's 288 FMAs.
__global__ __launch_bounds__(256, 2) void conv_back_kernel(
    const float* __restrict__ wu,
    const float* __restrict__ wl,
    const float* __restrict__ Tw,     // (8co, 72) transposed weights
    const float* __restrict__ bias,   // (8)
    float* __restrict__ outbuf,       // full d_out base
    float* __restrict__ bias_ws)      // (2,4,2048) partial bias sums
{
    const int bid = blockIdx.x;            // 0..2047
    const int klo = bid & 7;               // XCD id = k-chunk (k-disjoint)
    const int j   = bid >> 3;              // per-XCD order
    const int wig = j & 3;                 // wi group
    const int hr  = (j >> 2) & 7;          // 2-row group
    const int sl  = j >> 5;                // 0..7 (t,b)
    const int t = sl >> 2, b = sl & 3;
    const int kl  = threadIdx.x & 63;
    const int sub = threadIdx.x >> 6;      // 0..3
    const int wi  = wig * 4 + sub;         // 0..15, wave-uniform
    const int r0  = hr * 2;                // first owned out row
    const int k4  = klo * 64 + kl;         // f32x4 index over k, 0..511

    // uniform tensor bases (block-uniform) + ONE per-lane 32-bit offset
    const char* __restrict__ inb =
        (const char*)((t ? wl : wu) + (size_t)b * NOUT * NB);
    char* __restrict__ outb =
        (char*)(outbuf + (t ? OFF_WL : 0) + (size_t)b * NDIM * NB);
    const unsigned vo = (unsigned)(wi * 8 * NB4 + k4) * 16u;   // per-lane

    const bool vlo = wi > 0;               // wave-uniform edge masks
    const bool vhi = wi < 15;
    const int  dlo = -8 * NB4 * 16;        // byte deltas for wi-1 / wi+1
    const int  dhi =  8 * NB4 * 16;

    // block-uniform row validity / scalar byte offsets (co=0)
    bool rv[4];
    unsigned soff[4];
    #pragma unroll
    for (int s = 0; s < 4; ++s) {
        const int ho = r0 - 1 + s;
        rv[s] = ((unsigned)ho < 16u);
        soff[s] = rv[s] ? (unsigned)(ho * 128) * NB4 * 16u : 0u;
    }

    f32x4 acc[2][8];
    #pragma unroll
    for (int m = 0; m < 2; ++m)
        #pragma unroll
        for (int ci = 0; ci < 8; ++ci) acc[m][ci] = (f32x4)(0.f);
    f32x4 pb = (f32x4)(0.f);

    f32x4 uA[4][3], uB[4][3];

    // 12 loads: (uniform base + scalar (row,co) offset) + per-lane vo
    auto load = [&](int co, f32x4 (&u)[4][3]) {
        const unsigned cof = (unsigned)(co * NB4) * 16u;
        #pragma unroll
        for (int s = 0; s < 4; ++s) {
            if (rv[s]) {   // block-uniform branch
                const char* p = inb + (soff[s] + cof);       // scalar math
                u[s][1] = *(const f32x4*)(p + vo);
                u[s][0] = vlo ? *(const f32x4*)(p + (vo + dlo)) : (f32x4)(0.f);
                u[s][2] = vhi ? *(const f32x4*)(p + (vo + dhi)) : (f32x4)(0.f);
            } else {
                u[s][0] = (f32x4)(0.f);
                u[s][1] = (f32x4)(0.f);
                u[s][2] = (f32x4)(0.f);
            }
        }
    };

    auto fmaph = [&](int co, const f32x4 (&u)[4][3]) {
        const float* __restrict__ tb = Tw + co * 72;   // block-uniform -> SGPR
        const float bco = bias[co];
        pb += bco * (u[1][1] + u[2][1]);   // owned rows s=1,2, center col
        #pragma unroll
        for (int s = 0; s < 4; ++s)
            #pragma unroll
            for (int kh = 0; kh < 3; ++kh) {
                const int m = s - 2 + kh;           // target owned row
                if (m >= 0 && m <= 1) {             // compile-time filter
                    #pragma unroll
                    for (int ci = 0; ci < 8; ++ci)
                        #pragma unroll
                        for (int kw = 0; kw < 3; ++kw) {
                            const float Kv = tb[ci * 9 + kh * 3 + kw]; // SGPR
                            acc[m][ci] += Kv * u[s][2 - kw];   // dw = 1-kw
                        }
                }
            }
    };

    load(0, uA);
    #pragma unroll 1
    for (int c2 = 0; c2 < 4; ++c2) {
        const int co = c2 * 2;
        load(co + 1, uB);        // prefetch odd batch (flies under even FMAs)
        fmaph(co, uA);
        if (co + 2 < 8)
            load(co + 2, uA);    // prefetch next even batch
        fmaph(co + 1, uB);
    }

    #pragma unroll
    for (int m = 0; m < 2; ++m)
        #pragma unroll
        for (int ci = 0; ci < 8; ++ci) {
            const unsigned so = (unsigned)(((r0 + m) * 128 + ci) * NB4) * 16u;
            *(f32x4*)(outb + so + vo) = acc[m][ci];
        }

    // reduce bias partials across the 4 sub-waves (same k4, different wi)
    __shared__ f32x4 red[4][64];
    red[sub][kl] = pb;
    __syncthreads();
    if (sub == 0) {
        f32x4 tot = red[0][kl] + red[1][kl] + red[2][kl] + red[3][kl];
        float* bws = bias_ws + t * 8192 + b * 2048 + 4 * k4;
        atomicAdd(bws + 0, tot.x);
        atomicAdd(bws + 1, tot.y);
        atomicAdd(bws + 2, tot.z);
        atomicAdd(bws + 3, tot.w);
    }
}

// b_out_ = b_in + ws ; 16384 outputs (2 ul * 4 b * 2048 k)
__global__ void bias_finalize(const float* __restrict__ bu,
                              const float* __restrict__ bl,
                              const float* __restrict__ ws,
                              float* __restrict__ out)
{
    const int idx = blockIdx.x * blockDim.x + threadIdx.x;   // 0..16383
    const int ul  = idx >> 13;
    const int r   = idx & 8191;                              // b*2048 + k
    const float* bin = ul ? bl : bu;
    const size_t off = ul ? OFF_BL : OFF_BU;
    out[off + r] = bin[r] + ws[(size_t)ul * 8192 + r];
}

extern "C" void kernel_launch(void* const* d_in, const int* in_sizes, int n_in,
                              void* d_out, int out_size, void* d_ws, size_t ws_size,
                              hipStream_t stream) {
    // inputs: 0=x (unused), 1=kernel, 2=bias, 3=w_out_u, 4=b_out_u, 5=w_out_l, 6=b_out_l
    const float* kern = (const float*)d_in[1];
    const float* bias = (const float*)d_in[2];
    const float* wu   = (const float*)d_in[3];
    const float* bu   = (const float*)d_in[4];
    const float* wl   = (const float*)d_in[5];
    const float* bl   = (const float*)d_in[6];
    float* out = (float*)d_out;
    float* ws  = (float*)d_ws;

    // zero the 64 KB bias-partial region (graph replays re-run this node)
    (void)hipMemsetAsync(ws, 0, 2ull * 4 * NB * sizeof(float), stream);

    prep_kernel<<<9, 64, 0, stream>>>(kern, ws + WS_T);
    conv_back_kernel<<<dim3(2048), dim3(256), 0, stream>>>(wu, wl, ws + WS_T, bias, out, ws);
    bias_finalize<<<64, 256, 0, stream>>>(bu, bl, ws, out);
}

// Round 17
// 82.561 us; speedup vs baseline: 4.0400x; 1.3104x over previous
//
#include <hip/hip_runtime.h>

// Problem constants
#define NB    2048   // n_back (k)
#define NB4   512    // NB/4 in f32x4 units
#define NOUT  2048   // H*W*COUT
#define NDIM  2048   // H*W*CIN

// Output flat offsets (floats) in d_out: [w_u_, b_u_, w_l_, b_l_]
#define OFF_BU  16777216ull
#define OFF_WL  16785408ull
#define OFF_BL  33562624ull

// ws layout (floats): [0,16384) bias partials (2,4,2048); [16384,+576) T
#define WS_T    16384

typedef float f32x4 __attribute__((ext_vector_type(4)));

// T[co*72 + ci*9 + kh*3 + kw] = kern[((kh*3+kw)*8+ci)*8+co]
// -> per co, 72 CONTIGUOUS floats; block-uniform address -> s_load batches
// into the scalar file (round-10 mechanism; round-14: any threadIdx
// dependence here demotes weights to VMEM and destroys the kernel).
__global__ void prep_kernel(const float* __restrict__ kern, float* __restrict__ T) {
    const int i = blockIdx.x * 64 + threadIdx.x;   // 0..575
    if (i < 576) {
        const int kw = i % 3, kh = (i / 3) % 3, ci = (i / 9) % 8, co = i / 72;
        T[i] = kern[((kh * 3 + kw) * 8 + ci) * 8 + co];
    }
}

// 1-owned-row/thread conv-backward: TLP + batch-MLP together.
// r11 (3 w/SIMD, no batch) = 110us; r13 (2 w/SIMD, batch-12) = 93us; the
// ILP-only and TLP-only corners are both stalled. This round: batch-9
// (u[3][3]) with a 1-row tile (acc[1][8]) -> live set ~90 VGPR, so 4-5
// waves/SIMD coexist WITH the batch. Per co: 9 loads + 72 f32x4 FMAs;
// neighbor waves' FMA streams cover the LLC latency.
// launch_bounds(256,3): VGPR cap ~168 — above the live set, below spill
// territory (r12 lesson: cap 128 made the allocator spill, not shrink).
__global__ __launch_bounds__(256, 3) void conv_back_kernel(
    const float* __restrict__ wu,
    const float* __restrict__ wl,
    const float* __restrict__ Tw,     // (8co, 72) transposed weights
    const float* __restrict__ bias,   // (8)
    float* __restrict__ outbuf,       // full d_out base
    float* __restrict__ bias_ws)      // (2,4,2048) partial bias sums
{
    const int bid = blockIdx.x;            // 0..4095
    const int klo = bid & 7;               // XCD id = k-chunk (k-disjoint)
    const int j   = bid >> 3;              // per-XCD order, 0..511
    const int r   = j & 15;                // owned out row (fastest: halo loc.)
    const int wig = (j >> 4) & 3;          // wi group
    const int sl  = j >> 6;                // 0..7 (t,b)
    const int t = sl >> 2, b = sl & 3;
    const int kl  = threadIdx.x & 63;
    const int sub = threadIdx.x >> 6;      // 0..3
    const int wi  = wig * 4 + sub;         // 0..15, wave-uniform
    const int k4  = klo * 64 + kl;         // f32x4 index over k, 0..511

    const f32x4* __restrict__ in =
        (const f32x4*)(t ? wl : wu) + (size_t)b * NOUT * NB4 + k4;
    f32x4* __restrict__ wout =
        (f32x4*)(outbuf + (t ? OFF_WL : 0)) + (size_t)b * NDIM * NB4 + k4;

    const bool vlo = wi > 0;               // wave-uniform edge masks
    const bool vhi = wi < 15;

    // block-uniform row validity (s: in-row r-1+s, s=0..2)
    bool rv[3];
    rv[0] = (r > 0);
    rv[1] = true;
    rv[2] = (r < 15);

    f32x4 acc[8];
    #pragma unroll
    for (int ci = 0; ci < 8; ++ci) acc[ci] = (f32x4)(0.f);
    f32x4 pb = (f32x4)(0.f);

    #pragma unroll 1
    for (int co = 0; co < 8; ++co) {
        const float* __restrict__ tb = Tw + co * 72;  // block-uniform -> SGPR
        const float bco = bias[co];

        // ---- batched load phase: 9 loads in flight ----
        f32x4 u[3][3];                      // [s][wi-1, wi, wi+1]
        #pragma unroll
        for (int s = 0; s < 3; ++s) {
            if (rv[s]) {                    // block-uniform branch
                const int ho = r - 1 + s;
                const size_t base = (size_t)((ho * 16 + wi) * 8 + co) * NB4;
                u[s][0] = vlo ? in[base - 8 * NB4] : (f32x4)(0.f);
                u[s][1] =       in[base];
                u[s][2] = vhi ? in[base + 8 * NB4] : (f32x4)(0.f);
            } else {
                u[s][0] = (f32x4)(0.f);
                u[s][1] = (f32x4)(0.f);
                u[s][2] = (f32x4)(0.f);
            }
        }

        // owned row center column (in-row ho == r is s=1)
        pb += bco * u[1][1];

        // ---- FMA phase: 72 f32x4 FMAs ----
        // in-row ho = r-1+s feeds out row r with kh = 2-s (r7-verified map)
        #pragma unroll
        for (int s = 0; s < 3; ++s) {
            const int kh = 2 - s;
            #pragma unroll
            for (int ci = 0; ci < 8; ++ci)
                #pragma unroll
                for (int kw = 0; kw < 3; ++kw) {
                    const float Kv = tb[ci * 9 + kh * 3 + kw];  // SGPR
                    acc[ci] += Kv * u[s][2 - kw];               // dw = 1-kw
                }
        }
    }

    #pragma unroll
    for (int ci = 0; ci < 8; ++ci)
        wout[(size_t)((r * 16 + wi) * 8 + ci) * NB4] = acc[ci];

    // reduce bias partials across the 4 sub-waves (same k4, different wi)
    __shared__ f32x4 red[4][64];
    red[sub][kl] = pb;
    __syncthreads();
    if (sub == 0) {
        f32x4 tot = red[0][kl] + red[1][kl] + red[2][kl] + red[3][kl];
        float* bws = bias_ws + t * 8192 + b * 2048 + 4 * k4;
        atomicAdd(bws + 0, tot.x);
        atomicAdd(bws + 1, tot.y);
        atomicAdd(bws + 2, tot.z);
        atomicAdd(bws + 3, tot.w);
    }
}

// b_out_ = b_in + ws ; 16384 outputs (2 ul * 4 b * 2048 k)
__global__ void bias_finalize(const float* __restrict__ bu,
                              const float* __restrict__ bl,
                              const float* __restrict__ ws,
                              float* __restrict__ out)
{
    const int idx = blockIdx.x * blockDim.x + threadIdx.x;   // 0..16383
    const int ul  = idx >> 13;
    const int r   = idx & 8191;                              // b*2048 + k
    const float* bin = ul ? bl : bu;
    const size_t off = ul ? OFF_BL : OFF_BU;
    out[off + r] = bin[r] + ws[(size_t)ul * 8192 + r];
}

extern "C" void kernel_launch(void* const* d_in, const int* in_sizes, int n_in,
                              void* d_out, int out_size, void* d_ws, size_t ws_size,
                              hipStream_t stream) {
    // inputs: 0=x (unused), 1=kernel, 2=bias, 3=w_out_u, 4=b_out_u, 5=w_out_l, 6=b_out_l
    const float* kern = (const float*)d_in[1];
    const float* bias = (const float*)d_in[2];
    const float* wu   = (const float*)d_in[3];
    const float* bu   = (const float*)d_in[4];
    const float* wl   = (const float*)d_in[5];
    const float* bl   = (const float*)d_in[6];
    float* out = (float*)d_out;
    float* ws  = (float*)d_ws;

    // zero the 64 KB bias-partial region (graph replays re-run this node)
    (void)hipMemsetAsync(ws, 0, 2ull * 4 * NB * sizeof(float), stream);

    prep_kernel<<<9, 64, 0, stream>>>(kern, ws + WS_T);
    conv_back_kernel<<<dim3(4096), dim3(256), 0, stream>>>(wu, wl, ws + WS_T, bias, out, ws);
    bias_finalize<<<64, 256, 0, stream>>>(bu, bl, ws, out);
}